// Round 4
// baseline (1377.907 us; speedup 1.0000x reference)
//
#include <hip/hip_runtime.h>
#include <hip/hip_bf16.h>

// ---------------- problem constants ----------------
#define NROWS   32768      // B*S = 8*4096
#define DIN     2048
#define DOUT    2048
#define RANKS   64
#define NGROUP  32         // R / RP
#define TOPK    8
#define SCALING 2.0f       // lora_alpha(16) / activate_r(8)

typedef unsigned short ushort_t;
using bf16x8 = __attribute__((ext_vector_type(8))) short;
using f32x4  = __attribute__((ext_vector_type(4))) float;

__device__ __forceinline__ unsigned short f32_to_bf16_rne(float f) {
    union { float f; unsigned int u; } a; a.f = f;
    unsigned int r = a.u + 0x7FFFu + ((a.u >> 16) & 1u);
    return (unsigned short)(r >> 16);
}
__device__ __forceinline__ float bf16_bits_to_f32(unsigned short h) {
    union { unsigned int u; float f; } b; b.u = ((unsigned int)h) << 16;
    return b.f;
}
__device__ __forceinline__ void bf16split(float v, unsigned short& hi, unsigned short& lo) {
    hi = f32_to_bf16_rne(v);
    float r = v - bf16_bits_to_f32(hi);
    lo = f32_to_bf16_rne(r);
}
__device__ __forceinline__ void bf16split4(const float4& v, ushort4& h, ushort4& l) {
    unsigned short h0,h1,h2,h3,l0,l1,l2,l3;
    bf16split(v.x,h0,l0); bf16split(v.y,h1,l1);
    bf16split(v.z,h2,l2); bf16split(v.w,h3,l3);
    h = make_ushort4(h0,h1,h2,h3); l = make_ushort4(l0,l1,l2,l3);
}

// async global->LDS, 16B per lane; LDS dest is wave-uniform base (+lane*16 by HW)
__device__ __forceinline__ void gll16(const ushort_t* g, ushort_t* l) {
    __builtin_amdgcn_global_load_lds(
        (const __attribute__((address_space(1))) unsigned int*)g,
        (__attribute__((address_space(3))) unsigned int*)l,
        16, 0, 0);
}

// Split layout: row-major, per 32-k block: 64 ushorts = [hi k0..31 | lo k0..31].
// Row stride (ushorts): DIN*2=4096 for x/W/A, RANKS*2=128 for gmid/Bw.

// ================= Kernel 0: pre-split W, Bw, A =================
__global__ __launch_bounds__(256) void preconv_kernel(
    const float* __restrict__ W, const float* __restrict__ Bw,
    const float* __restrict__ A,
    ushort_t* __restrict__ Wsp, ushort_t* __restrict__ Bwsp,
    ushort_t* __restrict__ Asp)
{
    const int nW = DOUT * DIN / 4;
    const int nB = DOUT * RANKS / 4;
    const int nA = RANKS * DIN / 4;
    for (int i = blockIdx.x * blockDim.x + threadIdx.x; i < nW + nB + nA;
         i += gridDim.x * blockDim.x) {
        if (i < nW) {
            int e = i * 4; int row = e >> 11; int k = e & 2047;
            float4 v = *(const float4*)&W[e];
            ushort4 h, l; bf16split4(v, h, l);
            size_t base = (size_t)row * 4096 + (size_t)(k >> 5) * 64 + (k & 31);
            *(ushort4*)&Wsp[base]      = h;
            *(ushort4*)&Wsp[base + 32] = l;
        } else if (i < nW + nB) {
            int e = (i - nW) * 4; int row = e >> 6; int k = e & 63;
            float4 v = *(const float4*)&Bw[e];
            ushort4 h, l; bf16split4(v, h, l);
            size_t base = (size_t)row * 128 + (size_t)(k >> 5) * 64 + (k & 31);
            *(ushort4*)&Bwsp[base]      = h;
            *(ushort4*)&Bwsp[base + 32] = l;
        } else {
            int e = (i - nW - nB) * 4; int row = e >> 11; int k = e & 2047;
            float4 v = *(const float4*)&A[e];
            ushort4 h, l; bf16split4(v, h, l);
            size_t base = (size_t)row * 4096 + (size_t)(k >> 5) * 64 + (k & 31);
            *(ushort4*)&Asp[base]      = h;
            *(ushort4*)&Asp[base + 32] = l;
        }
    }
}

// ================= Kernel 1 v3: router(fp32 VALU) + mid(bf16x3 MFMA) + top-k =================
// Per block: 64 x-rows. Router dots (32 outs) in exact fp32 (top-k stability).
// Mid dots (64 outs) via mfma_16x16x32_bf16 x3 from split x (LDS) and split A (gll16).
#define NOUT 96

template<bool PRE>
__global__ __launch_bounds__(256) void router_mid_kernel(
    const float* __restrict__ x, const float* __restrict__ routerW,
    const float* __restrict__ biases, const ushort_t* __restrict__ Asp,
    ushort_t* __restrict__ gmidsp, ushort_t* __restrict__ Xsp)
{
    __shared__ __align__(16) char smem[58880];
    float*    xt   = (float*)smem;                 // [64][68] f32 x tile
    float*    wt   = (float*)(smem + 17408);       // [32][68] f32 routerW tile
    ushort_t* Axs  = (ushort_t*)(smem + 26112);    // [64][128] x split (swizzled)
    ushort_t* Bas  = (ushort_t*)(smem + 42496);    // [64][128] A split (swizzled)
    float*    dots = (float*)smem;                 // [64][96] aliases xt/wt after loop

    const int t    = threadIdx.x;
    const int n0   = blockIdx.x * 64;
    const int w    = t >> 6, lane = t & 63;
    const int lr   = lane & 15, lk = lane >> 4;
    const int r0   = t & 15;          // router: rows r0+16i (2-way bank = free)
    const int o0r  = (t >> 4) * 2;    // router: outs o0r..o0r+1 (broadcast)
    const int g16  = t >> 4;          // staging row-slot
    const int ko   = (t & 15) * 4;    // staging k-offset within 64-chunk

    float acc[4][2];
#pragma unroll
    for (int i = 0; i < 4; ++i) { acc[i][0] = 0.f; acc[i][1] = 0.f; }
    f32x4 accm[4];
#pragma unroll
    for (int f = 0; f < 4; ++f) accm[f] = f32x4{0.f, 0.f, 0.f, 0.f};

    for (int kc = 0; kc < DIN; kc += 64) {
        // ---- stage x (f32 tile + split to Axs + optional Xsp write) ----
#pragma unroll
        for (int p = 0; p < 4; ++p) {
            int row = p * 16 + g16;
            float4 v = *(const float4*)&x[(size_t)(n0 + row) * DIN + kc + ko];
            *(float4*)&xt[row * 68 + ko] = v;
            ushort4 h, l; bf16split4(v, h, l);
            if (PRE) {
                int k2 = kc + ko;
                size_t xb = (size_t)(n0 + row) * 4096 + (size_t)(k2 >> 5) * 64 + (k2 & 31);
                *(ushort4*)&Xsp[xb]      = h;
                *(ushort4*)&Xsp[xb + 32] = l;
            }
            int ks = ko >> 5, q = (ko & 31) >> 3, pos = ko & 7;
            *(ushort4*)&Axs[row * 128 + (ks * 8 + ( q      ^ (row & 7))) * 8 + pos] = h;
            *(ushort4*)&Axs[row * 128 + (ks * 8 + ((q + 4) ^ (row & 7))) * 8 + pos] = l;
        }
        // ---- stage routerW (f32, 32 rows) ----
#pragma unroll
        for (int p = 0; p < 2; ++p) {
            int row = p * 16 + g16;
            *(float4*)&wt[row * 68 + ko] =
                *(const float4*)&routerW[(size_t)row * DIN + kc + ko];
        }
        // ---- stage split-A via gll16 (pre-swizzled source, linear LDS dest) ----
        {
            int kb = kc >> 5;
#pragma unroll
            for (int c = 0; c < 4; ++c) {
                int chunk = w * 4 + c;                 // 16 chunks of 4 rows
                int row   = chunk * 4 + (lane >> 4);
                int sl    = lane & 15;                 // target 16B slot in row
                gll16(Asp + (size_t)row * 4096 + (size_t)(kb + (sl >> 3)) * 64
                          + ((sl & 7) ^ (row & 7)) * 8,
                      &Bas[chunk * 512]);
            }
        }
        __syncthreads();

        // ---- router fp32 dots (exact order: kk ascending, .x.y.z.w) ----
        for (int kk = 0; kk < 64; kk += 4) {
            float4 xv[4], wv[2];
#pragma unroll
            for (int i = 0; i < 4; ++i)
                xv[i] = *(const float4*)&xt[(r0 + 16 * i) * 68 + kk];
#pragma unroll
            for (int j = 0; j < 2; ++j)
                wv[j] = *(const float4*)&wt[(o0r + j) * 68 + kk];
#pragma unroll
            for (int i = 0; i < 4; ++i)
#pragma unroll
                for (int j = 0; j < 2; ++j) {
                    acc[i][j] += xv[i].x * wv[j].x;
                    acc[i][j] += xv[i].y * wv[j].y;
                    acc[i][j] += xv[i].z * wv[j].z;
                    acc[i][j] += xv[i].w * wv[j].w;
                }
        }
        // ---- mid MFMA (wave w: x-rows w*16..+15, A-cols 0..63) ----
#pragma unroll
        for (int ks = 0; ks < 2; ++ks) {
            int ar = w * 16 + lr;
            bf16x8 ah = *(const bf16x8*)&Axs[ar * 128 + (ks * 8 + ( lk      ^ (ar & 7))) * 8];
            bf16x8 al = *(const bf16x8*)&Axs[ar * 128 + (ks * 8 + ((lk + 4) ^ (ar & 7))) * 8];
#pragma unroll
            for (int f = 0; f < 4; ++f) {
                int br = f * 16 + lr;
                bf16x8 bh = *(const bf16x8*)&Bas[br * 128 + (ks * 8 + ( lk      ^ (br & 7))) * 8];
                bf16x8 bl = *(const bf16x8*)&Bas[br * 128 + (ks * 8 + ((lk + 4) ^ (br & 7))) * 8];
                accm[f] = __builtin_amdgcn_mfma_f32_16x16x32_bf16(ah, bh, accm[f], 0, 0, 0);
                accm[f] = __builtin_amdgcn_mfma_f32_16x16x32_bf16(ah, bl, accm[f], 0, 0, 0);
                accm[f] = __builtin_amdgcn_mfma_f32_16x16x32_bf16(al, bh, accm[f], 0, 0, 0);
            }
        }
        __syncthreads();
    }

    // ---- dump dots (aliases dead xt/wt) ----
#pragma unroll
    for (int i = 0; i < 4; ++i)
#pragma unroll
        for (int j = 0; j < 2; ++j)
            dots[(r0 + 16 * i) * NOUT + o0r + j] = acc[i][j];
#pragma unroll
    for (int f = 0; f < 4; ++f)
#pragma unroll
        for (int e = 0; e < 4; ++e)
            dots[(w * 16 + lk * 4 + e) * NOUT + 32 + f * 16 + lr] = accm[f][e];
    __syncthreads();

    // ---- top-k + gating (unchanged semantics) ----
    const float bia = biases[lane];
    for (int rr = w; rr < 64; rr += 4) {
        float glog  = dots[rr * NOUT + (lane >> 1)];
        float sig   = 1.0f / (1.0f + expf(-glog));
        float logit = sig + bia;
        float midv  = dots[rr * NOUT + 32 + lane];

        float mval = logit;
        int   sel  = 0;
        float ssum = 0.f;
#pragma unroll
        for (int it = 0; it < TOPK; ++it) {
            float v  = mval;
            int   ix = lane;
#pragma unroll
            for (int off = 1; off < 64; off <<= 1) {
                float ov = __shfl_xor(v, off);
                int   oi = __shfl_xor(ix, off);
                if (ov > v || (ov == v && oi < ix)) { v = ov; ix = oi; }
            }
            ssum += v;
            if (lane == ix) { sel = 1; mval = -1e30f; }
        }
        float gate = sel ? (logit / ssum) * (float)TOPK : 0.f;
        float gv   = midv * gate * SCALING;
        unsigned short gh, gl; bf16split(gv, gh, gl);
        size_t gb = (size_t)(n0 + rr) * 128 + (size_t)(lane >> 5) * 64 + (lane & 31);
        gmidsp[gb]      = gh;
        gmidsp[gb + 32] = gl;
    }
}

// ================= Kernel 2: fused bf16x3 GEMM  out = x.W^T + gmid.Bw^T =================
// UNCHANGED (measured 755 us, MfmaUtil 53.5%, 0 bank conflicts).
#define BM 128
#define BN 128
#define KSTEPS 66

template<bool PRE>
__global__ __launch_bounds__(256) void fused_gemm_kernel(
    const float* __restrict__ x, const ushort_t* __restrict__ Xsp,
    const ushort_t* __restrict__ gmidsp,
    const ushort_t* __restrict__ Wsp, const ushort_t* __restrict__ Bwsp,
    float* __restrict__ out)
{
    __shared__ __align__(16) ushort_t As[BM * 64];  // 16 KB
    __shared__ __align__(16) ushort_t Bs[BN * 64];  // 16 KB

    const int orig = blockIdx.x;
    const int q    = gridDim.x >> 3;
    const int wg   = (orig & 7) * q + (orig >> 3);
    const int cbase = (wg & 15) * BN;
    const int rbase = (wg >> 4) * BM;

    const int t = threadIdx.x;
    const int w = t >> 6, lane = t & 63;
    const int wr = w >> 1, wc = w & 1;
    const int lr = lane & 15, lk = lane >> 4;

    const int rowInChunk = lane >> 3;
    const int slotSrc    = (lane & 7) ^ rowInChunk;

    f32x4 acc[4][4];
#pragma unroll
    for (int i = 0; i < 4; ++i)
#pragma unroll
        for (int j = 0; j < 4; ++j) acc[i][j] = f32x4{0.f, 0.f, 0.f, 0.f};

    auto stageB = [&](int s) {
        const ushort_t* Bsrc; size_t bstr; int k0;
        if (s < 64) { Bsrc = Wsp;  bstr = 4096; k0 = s * 64; }
        else        { Bsrc = Bwsp; bstr = 128;  k0 = (s - 64) * 64; }
#pragma unroll
        for (int c = 0; c < 4; ++c) {
            int chunk = w * 4 + c;
            int row   = chunk * 8 + rowInChunk;
            gll16(Bsrc + (size_t)(cbase + row) * bstr + k0 + slotSrc * 8,
                  &Bs[chunk * 512]);
        }
    };
    auto stageA_pre = [&](int s) {
        const ushort_t* Asrc; size_t astr; int k0;
        if (s < 64) { Asrc = Xsp;    astr = 4096; k0 = s * 64; }
        else        { Asrc = gmidsp; astr = 128;  k0 = (s - 64) * 64; }
#pragma unroll
        for (int c = 0; c < 4; ++c) {
            int chunk = w * 4 + c;
            int row   = chunk * 8 + rowInChunk;
            gll16(Asrc + (size_t)(rbase + row) * astr + k0 + slotSrc * 8,
                  &As[chunk * 512]);
        }
    };
    auto stageA_reg = [&](int s) {
        const int srow = t >> 3;
        const int sq   = t & 7;
#pragma unroll
        for (int p = 0; p < 4; ++p) {
            int row = p * 32 + srow;
            float4 v = *(const float4*)&x[(size_t)(rbase + row) * DIN + s * 32 + sq * 4];
            ushort4 h, l; bf16split4(v, h, l);
            int shi = (sq >> 1) ^ (row & 7);
            int slo = ((sq >> 1) + 4) ^ (row & 7);
            int pos = (sq & 1) * 4;
            *(ushort4*)&As[row * 64 + shi * 8 + pos] = h;
            *(ushort4*)&As[row * 64 + slo * 8 + pos] = l;
        }
    };
    auto compute = [&]() {
        bf16x8 ah[4], al[4], bh[4], bl[4];
#pragma unroll
        for (int f = 0; f < 4; ++f) {
            int ar = wr * 64 + f * 16 + lr;
            ah[f] = *(const bf16x8*)&As[ar * 64 + ((lk       ^ (ar & 7)) * 8)];
            al[f] = *(const bf16x8*)&As[ar * 64 + (((lk + 4) ^ (ar & 7)) * 8)];
            int br = wc * 64 + f * 16 + lr;
            bh[f] = *(const bf16x8*)&Bs[br * 64 + ((lk       ^ (br & 7)) * 8)];
            bl[f] = *(const bf16x8*)&Bs[br * 64 + (((lk + 4) ^ (br & 7)) * 8)];
        }
#pragma unroll
        for (int i = 0; i < 4; ++i)
#pragma unroll
            for (int j = 0; j < 4; ++j) {
                acc[i][j] = __builtin_amdgcn_mfma_f32_16x16x32_bf16(ah[i], bh[j], acc[i][j], 0, 0, 0);
                acc[i][j] = __builtin_amdgcn_mfma_f32_16x16x32_bf16(ah[i], bl[j], acc[i][j], 0, 0, 0);
                acc[i][j] = __builtin_amdgcn_mfma_f32_16x16x32_bf16(al[i], bh[j], acc[i][j], 0, 0, 0);
            }
    };

    for (int s = 0; s < KSTEPS; ++s) {
        stageB(s);
        if (PRE || s >= 64) stageA_pre(s); else stageA_reg(s);
        __syncthreads();
        compute();
        __syncthreads();
    }

#pragma unroll
    for (int i = 0; i < 4; ++i)
#pragma unroll
        for (int j = 0; j < 4; ++j)
#pragma unroll
            for (int e = 0; e < 4; ++e) {
                int row = rbase + wr * 64 + i * 16 + lk * 4 + e;
                int col = cbase + wc * 64 + j * 16 + lr;
                out[(size_t)row * DOUT + col] = acc[i][j][e];
            }
}

// ================= launch =================
extern "C" void kernel_launch(void* const* d_in, const int* in_sizes, int n_in,
                              void* d_out, int out_size, void* d_ws, size_t ws_size,
                              hipStream_t stream) {
    (void)in_sizes; (void)n_in; (void)out_size;
    const float* x       = (const float*)d_in[0];
    const float* baseW   = (const float*)d_in[1];
    const float* routerW = (const float*)d_in[2];
    const float* A       = (const float*)d_in[3];
    const float* Bw      = (const float*)d_in[4];
    const float* biases  = (const float*)d_in[5];
    float* out = (float*)d_out;

    char* p = (char*)d_ws;
    ushort_t* Wsp    = (ushort_t*)p;               //  16,777,216 B
    ushort_t* Bwsp   = (ushort_t*)(p + 16777216);  //     524,288 B
    ushort_t* Asp    = (ushort_t*)(p + 17301504);  //     524,288 B
    ushort_t* gmidsp = (ushort_t*)(p + 17825792);  //   8,388,608 B
    ushort_t* Xsp    = (ushort_t*)(p + 26214400);  // 268,435,456 B (PRE only)
    const bool pre = ws_size >= 26214400ull + 268435456ull;

    hipLaunchKernelGGL(preconv_kernel, dim3(1024), dim3(256), 0, stream,
                       baseW, Bw, A, Wsp, Bwsp, Asp);
    if (pre) {
        hipLaunchKernelGGL((router_mid_kernel<true>), dim3(NROWS / 64), dim3(256), 0,
                           stream, x, routerW, biases, Asp, gmidsp, Xsp);
        hipLaunchKernelGGL((fused_gemm_kernel<true>), dim3((NROWS / BM) * (DOUT / BN)),
                           dim3(256), 0, stream, x, Xsp, gmidsp, Wsp, Bwsp, out);
    } else {
        hipLaunchKernelGGL((router_mid_kernel<false>), dim3(NROWS / 64), dim3(256), 0,
                           stream, x, routerW, biases, Asp, gmidsp, Xsp);
        hipLaunchKernelGGL((fused_gemm_kernel<false>), dim3((NROWS / BM) * (DOUT / BN)),
                           dim3(256), 0, stream, x, Xsp, gmidsp, Wsp, Bwsp, out);
    }
}

// Round 5
// 1290.084 us; speedup vs baseline: 1.0681x; 1.0681x over previous
//
#include <hip/hip_runtime.h>
#include <hip/hip_bf16.h>

// ---------------- problem constants ----------------
#define NROWS   32768      // B*S = 8*4096
#define DIN     2048
#define DOUT    2048
#define RANKS   64
#define NGROUP  32         // R / RP
#define TOPK    8
#define SCALING 2.0f       // lora_alpha(16) / activate_r(8)

typedef unsigned short ushort_t;
using bf16x8 = __attribute__((ext_vector_type(8))) short;
using f32x4  = __attribute__((ext_vector_type(4))) float;

__device__ __forceinline__ unsigned short f32_to_bf16_rne(float f) {
    union { float f; unsigned int u; } a; a.f = f;
    unsigned int r = a.u + 0x7FFFu + ((a.u >> 16) & 1u);
    return (unsigned short)(r >> 16);
}
__device__ __forceinline__ float bf16_bits_to_f32(unsigned short h) {
    union { unsigned int u; float f; } b; b.u = ((unsigned int)h) << 16;
    return b.f;
}
__device__ __forceinline__ void bf16split(float v, unsigned short& hi, unsigned short& lo) {
    hi = f32_to_bf16_rne(v);
    float r = v - bf16_bits_to_f32(hi);
    lo = f32_to_bf16_rne(r);
}
__device__ __forceinline__ void bf16split4(const float4& v, ushort4& h, ushort4& l) {
    unsigned short h0,h1,h2,h3,l0,l1,l2,l3;
    bf16split(v.x,h0,l0); bf16split(v.y,h1,l1);
    bf16split(v.z,h2,l2); bf16split(v.w,h3,l3);
    h = make_ushort4(h0,h1,h2,h3); l = make_ushort4(l0,l1,l2,l3);
}

// async global->LDS, 16B per lane; LDS dest is wave-uniform base (+lane*16 by HW)
__device__ __forceinline__ void gll16(const ushort_t* g, ushort_t* l) {
    __builtin_amdgcn_global_load_lds(
        (const __attribute__((address_space(1))) unsigned int*)g,
        (__attribute__((address_space(3))) unsigned int*)l,
        16, 0, 0);
}

// Split layout: row-major, per 32-k block: 64 ushorts = [hi k0..31 | lo k0..31].
// Row stride (ushorts): DIN*2=4096 for x/W/A, RANKS*2=128 for gmid/Bw.

// ================= Kernel 0: pre-split W, Bw, A  (UNCHANGED) =================
__global__ __launch_bounds__(256) void preconv_kernel(
    const float* __restrict__ W, const float* __restrict__ Bw,
    const float* __restrict__ A,
    ushort_t* __restrict__ Wsp, ushort_t* __restrict__ Bwsp,
    ushort_t* __restrict__ Asp)
{
    const int nW = DOUT * DIN / 4;
    const int nB = DOUT * RANKS / 4;
    const int nA = RANKS * DIN / 4;
    for (int i = blockIdx.x * blockDim.x + threadIdx.x; i < nW + nB + nA;
         i += gridDim.x * blockDim.x) {
        if (i < nW) {
            int e = i * 4; int row = e >> 11; int k = e & 2047;
            float4 v = *(const float4*)&W[e];
            ushort4 h, l; bf16split4(v, h, l);
            size_t base = (size_t)row * 4096 + (size_t)(k >> 5) * 64 + (k & 31);
            *(ushort4*)&Wsp[base]      = h;
            *(ushort4*)&Wsp[base + 32] = l;
        } else if (i < nW + nB) {
            int e = (i - nW) * 4; int row = e >> 6; int k = e & 63;
            float4 v = *(const float4*)&Bw[e];
            ushort4 h, l; bf16split4(v, h, l);
            size_t base = (size_t)row * 128 + (size_t)(k >> 5) * 64 + (k & 31);
            *(ushort4*)&Bwsp[base]      = h;
            *(ushort4*)&Bwsp[base + 32] = l;
        } else {
            int e = (i - nW - nB) * 4; int row = e >> 11; int k = e & 2047;
            float4 v = *(const float4*)&A[e];
            ushort4 h, l; bf16split4(v, h, l);
            size_t base = (size_t)row * 4096 + (size_t)(k >> 5) * 64 + (k & 31);
            *(ushort4*)&Asp[base]      = h;
            *(ushort4*)&Asp[base + 32] = l;
        }
    }
}

// ================= Kernel 1: router + mid + top-k  (UNCHANGED from round 4) ==========
#define NOUT 96

template<bool PRE>
__global__ __launch_bounds__(256) void router_mid_kernel(
    const float* __restrict__ x, const float* __restrict__ routerW,
    const float* __restrict__ biases, const ushort_t* __restrict__ Asp,
    ushort_t* __restrict__ gmidsp, ushort_t* __restrict__ Xsp)
{
    __shared__ __align__(16) char smem[58880];
    float*    xt   = (float*)smem;                 // [64][68] f32 x tile
    float*    wt   = (float*)(smem + 17408);       // [32][68] f32 routerW tile
    ushort_t* Axs  = (ushort_t*)(smem + 26112);    // [64][128] x split (swizzled)
    ushort_t* Bas  = (ushort_t*)(smem + 42496);    // [64][128] A split (swizzled)
    float*    dots = (float*)smem;                 // [64][96] aliases xt/wt after loop

    const int t    = threadIdx.x;
    const int n0   = blockIdx.x * 64;
    const int w    = t >> 6, lane = t & 63;
    const int lr   = lane & 15, lk = lane >> 4;
    const int r0   = t & 15;
    const int o0r  = (t >> 4) * 2;
    const int g16  = t >> 4;
    const int ko   = (t & 15) * 4;

    float acc[4][2];
#pragma unroll
    for (int i = 0; i < 4; ++i) { acc[i][0] = 0.f; acc[i][1] = 0.f; }
    f32x4 accm[4];
#pragma unroll
    for (int f = 0; f < 4; ++f) accm[f] = f32x4{0.f, 0.f, 0.f, 0.f};

    for (int kc = 0; kc < DIN; kc += 64) {
#pragma unroll
        for (int p = 0; p < 4; ++p) {
            int row = p * 16 + g16;
            float4 v = *(const float4*)&x[(size_t)(n0 + row) * DIN + kc + ko];
            *(float4*)&xt[row * 68 + ko] = v;
            ushort4 h, l; bf16split4(v, h, l);
            if (PRE) {
                int k2 = kc + ko;
                size_t xb = (size_t)(n0 + row) * 4096 + (size_t)(k2 >> 5) * 64 + (k2 & 31);
                *(ushort4*)&Xsp[xb]      = h;
                *(ushort4*)&Xsp[xb + 32] = l;
            }
            int ks = ko >> 5, q = (ko & 31) >> 3, pos = ko & 7;
            *(ushort4*)&Axs[row * 128 + (ks * 8 + ( q      ^ (row & 7))) * 8 + pos] = h;
            *(ushort4*)&Axs[row * 128 + (ks * 8 + ((q + 4) ^ (row & 7))) * 8 + pos] = l;
        }
#pragma unroll
        for (int p = 0; p < 2; ++p) {
            int row = p * 16 + g16;
            *(float4*)&wt[row * 68 + ko] =
                *(const float4*)&routerW[(size_t)row * DIN + kc + ko];
        }
        {
            int kb = kc >> 5;
#pragma unroll
            for (int c = 0; c < 4; ++c) {
                int chunk = w * 4 + c;
                int row   = chunk * 4 + (lane >> 4);
                int sl    = lane & 15;
                gll16(Asp + (size_t)row * 4096 + (size_t)(kb + (sl >> 3)) * 64
                          + ((sl & 7) ^ (row & 7)) * 8,
                      &Bas[chunk * 512]);
            }
        }
        __syncthreads();

        for (int kk = 0; kk < 64; kk += 4) {
            float4 xv[4], wv[2];
#pragma unroll
            for (int i = 0; i < 4; ++i)
                xv[i] = *(const float4*)&xt[(r0 + 16 * i) * 68 + kk];
#pragma unroll
            for (int j = 0; j < 2; ++j)
                wv[j] = *(const float4*)&wt[(o0r + j) * 68 + kk];
#pragma unroll
            for (int i = 0; i < 4; ++i)
#pragma unroll
                for (int j = 0; j < 2; ++j) {
                    acc[i][j] += xv[i].x * wv[j].x;
                    acc[i][j] += xv[i].y * wv[j].y;
                    acc[i][j] += xv[i].z * wv[j].z;
                    acc[i][j] += xv[i].w * wv[j].w;
                }
        }
#pragma unroll
        for (int ks = 0; ks < 2; ++ks) {
            int ar = w * 16 + lr;
            bf16x8 ah = *(const bf16x8*)&Axs[ar * 128 + (ks * 8 + ( lk      ^ (ar & 7))) * 8];
            bf16x8 al = *(const bf16x8*)&Axs[ar * 128 + (ks * 8 + ((lk + 4) ^ (ar & 7))) * 8];
#pragma unroll
            for (int f = 0; f < 4; ++f) {
                int br = f * 16 + lr;
                bf16x8 bh = *(const bf16x8*)&Bas[br * 128 + (ks * 8 + ( lk      ^ (br & 7))) * 8];
                bf16x8 bl = *(const bf16x8*)&Bas[br * 128 + (ks * 8 + ((lk + 4) ^ (br & 7))) * 8];
                accm[f] = __builtin_amdgcn_mfma_f32_16x16x32_bf16(ah, bh, accm[f], 0, 0, 0);
                accm[f] = __builtin_amdgcn_mfma_f32_16x16x32_bf16(ah, bl, accm[f], 0, 0, 0);
                accm[f] = __builtin_amdgcn_mfma_f32_16x16x32_bf16(al, bh, accm[f], 0, 0, 0);
            }
        }
        __syncthreads();
    }

#pragma unroll
    for (int i = 0; i < 4; ++i)
#pragma unroll
        for (int j = 0; j < 2; ++j)
            dots[(r0 + 16 * i) * NOUT + o0r + j] = acc[i][j];
#pragma unroll
    for (int f = 0; f < 4; ++f)
#pragma unroll
        for (int e = 0; e < 4; ++e)
            dots[(w * 16 + lk * 4 + e) * NOUT + 32 + f * 16 + lr] = accm[f][e];
    __syncthreads();

    const float bia = biases[lane];
    for (int rr = w; rr < 64; rr += 4) {
        float glog  = dots[rr * NOUT + (lane >> 1)];
        float sig   = 1.0f / (1.0f + expf(-glog));
        float logit = sig + bia;
        float midv  = dots[rr * NOUT + 32 + lane];

        float mval = logit;
        int   sel  = 0;
        float ssum = 0.f;
#pragma unroll
        for (int it = 0; it < TOPK; ++it) {
            float v  = mval;
            int   ix = lane;
#pragma unroll
            for (int off = 1; off < 64; off <<= 1) {
                float ov = __shfl_xor(v, off);
                int   oi = __shfl_xor(ix, off);
                if (ov > v || (ov == v && oi < ix)) { v = ov; ix = oi; }
            }
            ssum += v;
            if (lane == ix) { sel = 1; mval = -1e30f; }
        }
        float gate = sel ? (logit / ssum) * (float)TOPK : 0.f;
        float gv   = midv * gate * SCALING;
        unsigned short gh, gl; bf16split(gv, gh, gl);
        size_t gb = (size_t)(n0 + rr) * 128 + (size_t)(lane >> 5) * 64 + (lane & 31);
        gmidsp[gb]      = gh;
        gmidsp[gb + 32] = gl;
    }
}

// ================= Kernel 2 v3: 256x256 deep-pipelined bf16x3 GEMM =================
// out = x.W^T + gmid.Bw^T.  8 waves (2M x 4N), per-wave 128x64 (8x4 frags).
// Double-buffered 32KB A/B tiles (128 KB LDS, 1 block/CU, 2 waves/SIMD).
// Per chunk: 4 phases {ds_read subtile -> MFMA cluster}; stage chunk t+2 into the
// just-freed buffer at P3 (after barrier), counted vmcnt(8) keeps t+2's loads in
// flight across the iteration boundary (never drains to 0 in main loop).
#define KCH 66

template<bool PRE>
__global__ __launch_bounds__(512, 2) void fused_gemm_kernel(
    const float* __restrict__ x, const ushort_t* __restrict__ Xsp,
    const ushort_t* __restrict__ gmidsp,
    const ushort_t* __restrict__ Wsp, const ushort_t* __restrict__ Bwsp,
    float* __restrict__ out)
{
    __shared__ __align__(16) ushort_t As[2][256 * 64];  // 64 KB
    __shared__ __align__(16) ushort_t Bs[2][256 * 64];  // 64 KB

    // bijective XCD swizzle (nwg=1024, %8==0); col-fast within chunk
    const int orig = blockIdx.x;
    const int qx   = gridDim.x >> 3;
    const int wg   = (orig & 7) * qx + (orig >> 3);
    const int cbase = (wg & 7) * 256;
    const int rbase = (wg >> 3) * 256;

    const int t = threadIdx.x;
    const int w = t >> 6, lane = t & 63;
    const int wr = w >> 2, wc = w & 3;          // wave tile: rows wr*128, cols wc*64
    const int lr = lane & 15, lk = lane >> 4;

    const int ric     = lane >> 3;              // row in 8-row chunk
    const int slotSrc = (lane & 7) ^ ric;       // pre-swizzled source slot

    f32x4 acc[8][4];
#pragma unroll
    for (int i = 0; i < 8; ++i)
#pragma unroll
        for (int j = 0; j < 4; ++j) acc[i][j] = f32x4{0.f, 0.f, 0.f, 0.f};

    // ---- staging: wave w covers A-chunks & B-chunks [w*4, w*4+4) (8 rows each) ----
    auto stage = [&](int s, int buf) {
        const ushort_t *Bsrc; size_t bstr; int k0;
        if (s < 64) { Bsrc = Wsp;  bstr = 4096; k0 = s * 64; }
        else        { Bsrc = Bwsp; bstr = 128;  k0 = (s - 64) * 64; }
#pragma unroll
        for (int c = 0; c < 4; ++c) {
            int ch  = w * 4 + c;
            int row = ch * 8 + ric;
            gll16(Bsrc + (size_t)(cbase + row) * bstr + k0 + slotSrc * 8,
                  &Bs[buf][ch * 512]);
        }
        if (PRE || s >= 64) {
            const ushort_t *Asrc; size_t astr;
            if (s < 64) { Asrc = Xsp;    astr = 4096; }
            else        { Asrc = gmidsp; astr = 128;  }
#pragma unroll
            for (int c = 0; c < 4; ++c) {
                int ch  = w * 4 + c;
                int row = ch * 8 + ric;
                gll16(Asrc + (size_t)(rbase + row) * astr + k0 + slotSrc * 8,
                      &As[buf][ch * 512]);
            }
        } else {
            // fallback: split x on the fly, swizzled ds_write (512 thr x 16 floats)
            const int srow  = t >> 1;
            const int shalf = t & 1;
#pragma unroll
            for (int p = 0; p < 4; ++p) {
                int kl = shalf * 16 + p * 4;
                float4 v = *(const float4*)&x[(size_t)(rbase + srow) * DIN + s * 32 + kl];
                ushort4 h, l; bf16split4(v, h, l);
                int nomH = kl >> 3, pos = kl & 7;
                *(ushort4*)&As[buf][srow * 64 + ((nomH       ^ (srow & 7)) * 8) + pos] = h;
                *(ushort4*)&As[buf][srow * 64 + (((nomH + 4) ^ (srow & 7)) * 8) + pos] = l;
            }
        }
    };

    // ---- per-chunk compute phases ----
    bf16x8 bhf[4], blf[4];
    auto loadB = [&](int buf) {
#pragma unroll
        for (int n = 0; n < 4; ++n) {
            int br = wc * 64 + n * 16 + lr;
            bhf[n] = *(const bf16x8*)&Bs[buf][br * 64 + ((lk       ^ (br & 7)) * 8)];
            blf[n] = *(const bf16x8*)&Bs[buf][br * 64 + (((lk + 4) ^ (br & 7)) * 8)];
        }
    };
    auto mfmaPair = [&](int buf, int p) {  // A-rows m=2p, 2p+1  x  all 4 N-frags
        bf16x8 ah[2], al[2];
#pragma unroll
        for (int u = 0; u < 2; ++u) {
            int ar = wr * 128 + (2 * p + u) * 16 + lr;
            ah[u] = *(const bf16x8*)&As[buf][ar * 64 + ((lk       ^ (ar & 7)) * 8)];
            al[u] = *(const bf16x8*)&As[buf][ar * 64 + (((lk + 4) ^ (ar & 7)) * 8)];
        }
        __builtin_amdgcn_s_setprio(1);
#pragma unroll
        for (int u = 0; u < 2; ++u)
#pragma unroll
            for (int n = 0; n < 4; ++n) {
                int m = 2 * p + u;
                acc[m][n] = __builtin_amdgcn_mfma_f32_16x16x32_bf16(ah[u], bhf[n], acc[m][n], 0, 0, 0);
                acc[m][n] = __builtin_amdgcn_mfma_f32_16x16x32_bf16(ah[u], blf[n], acc[m][n], 0, 0, 0);
                acc[m][n] = __builtin_amdgcn_mfma_f32_16x16x32_bf16(al[u], bhf[n], acc[m][n], 0, 0, 0);
            }
        __builtin_amdgcn_s_setprio(0);
    };

    // ---- prologue: stage chunks 0,1; wait chunk 0 landed ----
    stage(0, 0);
    stage(1, 1);
    if (PRE) { asm volatile("s_waitcnt vmcnt(8)" ::: "memory"); }
    else     { asm volatile("s_waitcnt vmcnt(4) lgkmcnt(0)" ::: "memory"); }
    __builtin_amdgcn_sched_barrier(0);
    __builtin_amdgcn_s_barrier();

    // ---- main loop ----
    for (int tt = 0; tt < KCH; ++tt) {
        const int cur = tt & 1;
        // P0..P2: B-frags + A-pairs 0..2
        loadB(cur);
        mfmaPair(cur, 0);
        mfmaPair(cur, 1);
        mfmaPair(cur, 2);
        // P3: last A-pair reads, then free the buffer and restage it
        bf16x8 ah[2], al[2];
#pragma unroll
        for (int u = 0; u < 2; ++u) {
            int ar = wr * 128 + (6 + u) * 16 + lr;
            ah[u] = *(const bf16x8*)&As[cur][ar * 64 + ((lk       ^ (ar & 7)) * 8)];
            al[u] = *(const bf16x8*)&As[cur][ar * 64 + (((lk + 4) ^ (ar & 7)) * 8)];
        }
        asm volatile("s_waitcnt lgkmcnt(0)" ::: "memory");   // my reads of buf[cur] done
        __builtin_amdgcn_sched_barrier(0);
        __builtin_amdgcn_s_barrier();                        // all waves done with buf[cur]
        if (tt + 2 < KCH) stage(tt + 2, cur);                // refill freed buffer (async)
        __builtin_amdgcn_s_setprio(1);
#pragma unroll
        for (int u = 0; u < 2; ++u)
#pragma unroll
            for (int n = 0; n < 4; ++n) {
                int m = 6 + u;
                acc[m][n] = __builtin_amdgcn_mfma_f32_16x16x32_bf16(ah[u], bhf[n], acc[m][n], 0, 0, 0);
                acc[m][n] = __builtin_amdgcn_mfma_f32_16x16x32_bf16(ah[u], blf[n], acc[m][n], 0, 0, 0);
                acc[m][n] = __builtin_amdgcn_mfma_f32_16x16x32_bf16(al[u], bhf[n], acc[m][n], 0, 0, 0);
            }
        __builtin_amdgcn_s_setprio(0);
        // gate: chunk tt+1 landed (leave tt+2's loads in flight)
        if (tt + 2 < KCH) {
            if (PRE) { asm volatile("s_waitcnt vmcnt(8)" ::: "memory"); }
            else     { asm volatile("s_waitcnt vmcnt(4) lgkmcnt(0)" ::: "memory"); }
        } else {
            asm volatile("s_waitcnt vmcnt(0) lgkmcnt(0)" ::: "memory");
        }
        __builtin_amdgcn_sched_barrier(0);
        __builtin_amdgcn_s_barrier();
    }

    // ---- epilogue: C/D col=lane&15, row=(lane>>4)*4+e  [m89-verified] ----
#pragma unroll
    for (int m = 0; m < 8; ++m)
#pragma unroll
        for (int n = 0; n < 4; ++n)
#pragma unroll
            for (int e = 0; e < 4; ++e) {
                int row = rbase + wr * 128 + m * 16 + lk * 4 + e;
                int col = cbase + wc * 64 + n * 16 + lr;
                out[(size_t)row * DOUT + col] = acc[m][n][e];
            }
}

// ================= launch =================
extern "C" void kernel_launch(void* const* d_in, const int* in_sizes, int n_in,
                              void* d_out, int out_size, void* d_ws, size_t ws_size,
                              hipStream_t stream) {
    (void)in_sizes; (void)n_in; (void)out_size;
    const float* x       = (const float*)d_in[0];
    const float* baseW   = (const float*)d_in[1];
    const float* routerW = (const float*)d_in[2];
    const float* A       = (const float*)d_in[3];
    const float* Bw      = (const float*)d_in[4];
    const float* biases  = (const float*)d_in[5];
    float* out = (float*)d_out;

    char* p = (char*)d_ws;
    ushort_t* Wsp    = (ushort_t*)p;               //  16,777,216 B
    ushort_t* Bwsp   = (ushort_t*)(p + 16777216);  //     524,288 B
    ushort_t* Asp    = (ushort_t*)(p + 17301504);  //     524,288 B
    ushort_t* gmidsp = (ushort_t*)(p + 17825792);  //   8,388,608 B
    ushort_t* Xsp    = (ushort_t*)(p + 26214400);  // 268,435,456 B (PRE only)
    const bool pre = ws_size >= 26214400ull + 268435456ull;

    hipLaunchKernelGGL(preconv_kernel, dim3(1024), dim3(256), 0, stream,
                       baseW, Bw, A, Wsp, Bwsp, Asp);
    if (pre) {
        hipLaunchKernelGGL((router_mid_kernel<true>), dim3(NROWS / 64), dim3(256), 0,
                           stream, x, routerW, biases, Asp, gmidsp, Xsp);
        hipLaunchKernelGGL((fused_gemm_kernel<true>), dim3((NROWS / 256) * (DOUT / 256)),
                           dim3(512), 0, stream, x, Xsp, gmidsp, Wsp, Bwsp, out);
    } else {
        hipLaunchKernelGGL((router_mid_kernel<false>), dim3(NROWS / 64), dim3(256), 0,
                           stream, x, routerW, biases, Asp, gmidsp, Xsp);
        hipLaunchKernelGGL((fused_gemm_kernel<false>), dim3((NROWS / 256) * (DOUT / 256)),
                           dim3(512), 0, stream, x, Xsp, gmidsp, Wsp, Bwsp, out);
    }
}